// Round 1
// baseline (296.310 us; speedup 1.0000x reference)
//
#include <hip/hip_runtime.h>
#include <math.h>

#define N_HITS 65536
#define K_INST 512
#define D_EMB  32
#define MARGIN 0.3f
#define BPB    64      // blocks per batch in main kernel

// ---------------------------------------------------------------------------
// Kernel 1: first_cp via atomicMin, pos count per batch
// ---------------------------------------------------------------------------
__global__ void k_scan(const int* __restrict__ sid, const int* __restrict__ iscp,
                       int* first_cp, int* pos_cnt) {
    int b = blockIdx.y;
    int i = blockIdx.x * blockDim.x + threadIdx.x;
    int stride = gridDim.x * blockDim.x;
    for (; i < N_HITS; i += stride) {
        int c = iscp[b * N_HITS + i];
        if (c == 1) {
            atomicAdd(&pos_cnt[b], 1);
            int s = sid[b * N_HITS + i];
            if (s >= 0) atomicMin(&first_cp[b * K_INST + s], i);
        }
    }
}

// ---------------------------------------------------------------------------
// Kernel 2: gather cp_emb / cp_beta with safe_cp = min(first_cp, N-1)
// ---------------------------------------------------------------------------
__global__ void k_gather(const float* __restrict__ beta, const float4* __restrict__ embed4,
                         const int* __restrict__ first_cp,
                         float* cp_beta, float4* cp_emb4, int B) {
    int g = blockIdx.x * blockDim.x + threadIdx.x;
    int total = B * K_INST * 8;
    if (g >= total) return;
    int row = g >> 3, sub = g & 7;
    int b = row / K_INST;
    int fc = first_cp[row];
    int safe = min(fc, N_HITS - 1);
    cp_emb4[(size_t)row * 8 + sub] = embed4[((size_t)b * N_HITS + safe) * 8 + sub];
    if (sub == 0) cp_beta[row] = beta[b * N_HITS + safe];
}

// ---------------------------------------------------------------------------
// Kernel 3: main streaming pass. 8 lanes per hit, LDS segment bins.
// ---------------------------------------------------------------------------
__global__ __launch_bounds__(256) void k_main(
    const float*  __restrict__ beta,  const float4* __restrict__ embed4,
    const int*    __restrict__ sid_g, const int*    __restrict__ iscp_g,
    const float4* __restrict__ cp_emb4, const float* __restrict__ cp_beta,
    int* cnt_packed, float* seg_d2, float* seg_r,
    float* s_cp, float* s_ncp, float* s_bg) {
    __shared__ int   l_cnt[K_INST];
    __shared__ float l_d2[K_INST];
    __shared__ float l_r[K_INST];
    __shared__ float l_red[12];

    int b = blockIdx.y;
    int tid = threadIdx.x;
    for (int k = tid; k < K_INST; k += 256) { l_cnt[k] = 0; l_d2[k] = 0.f; l_r[k] = 0.f; }
    __syncthreads();

    int sub = tid & 7, hid = tid >> 3;         // 8 lanes per hit, 32 hits/iter
    const int hits = N_HITS / BPB;             // 1024
    int base = blockIdx.x * hits;
    float a_cp = 0.f, a_ncp = 0.f, a_bg = 0.f;

    for (int it = 0; it < hits / 32; ++it) {
        int i = base + it * 32 + hid;
        int s = sid_g[b * N_HITS + i];
        int c = iscp_g[b * N_HITS + i];
        bool cp = (c == 1), valid = (s >= 0), noncp = valid && !cp;
        int sc = min(max(s, 0), K_INST - 1);

        float4 e  = embed4[((size_t)b * N_HITS + i) * 8 + sub];
        float4 ce = cp_emb4[((size_t)b * K_INST + sc) * 8 + sub];
        float dx = e.x - ce.x, dy = e.y - ce.y, dz = e.z - ce.z, dw = e.w - ce.w;
        float d2 = dx * dx + dy * dy + dz * dz + dw * dw;
        d2 += __shfl_xor(d2, 1);
        d2 += __shfl_xor(d2, 2);
        d2 += __shfl_xor(d2, 4);

        if (sub == 0) {
            float x = beta[b * N_HITS + i];
            float bce = fmaxf(x, 0.f) - (cp ? x : 0.f) + log1pf(__expf(-fabsf(x)));
            if (cp) a_cp += bce; else if (noncp) a_ncp += bce; else a_bg += bce;
            if (valid) {
                atomicAdd(&l_cnt[s], cp ? (1 << 20) : 1);
                atomicAdd(&l_d2[s], d2);
                if (noncp) {
                    float r = fmaxf(x + MARGIN - cp_beta[b * K_INST + s], 0.f);
                    atomicAdd(&l_r[s], r);
                }
            }
        }
    }

    // block-reduce the three BCE class sums
    for (int o = 32; o > 0; o >>= 1) {
        a_cp  += __shfl_down(a_cp, o);
        a_ncp += __shfl_down(a_ncp, o);
        a_bg  += __shfl_down(a_bg, o);
    }
    int wave = tid >> 6;
    if ((tid & 63) == 0) { l_red[wave] = a_cp; l_red[4 + wave] = a_ncp; l_red[8 + wave] = a_bg; }
    __syncthreads();
    if (tid == 0) {
        atomicAdd(&s_cp[b],  l_red[0] + l_red[1] + l_red[2]  + l_red[3]);
        atomicAdd(&s_ncp[b], l_red[4] + l_red[5] + l_red[6]  + l_red[7]);
        atomicAdd(&s_bg[b],  l_red[8] + l_red[9] + l_red[10] + l_red[11]);
    }
    // merge LDS bins to global
    for (int k = tid; k < K_INST; k += 256) {
        int   cv = l_cnt[k]; if (cv)        atomicAdd(&cnt_packed[b * K_INST + k], cv);
        float dv = l_d2[k];  if (dv != 0.f) atomicAdd(&seg_d2[b * K_INST + k], dv);
        float rv = l_r[k];   if (rv != 0.f) atomicAdd(&seg_r[b * K_INST + k], rv);
    }
}

// ---------------------------------------------------------------------------
// Kernel 4: per-segment finalize -> per-batch attr / rank_sum / n_unique
// ---------------------------------------------------------------------------
__global__ __launch_bounds__(512) void k_seg(
    const int* __restrict__ cnt_packed, const float* __restrict__ seg_d2,
    const float* __restrict__ seg_r, const int* __restrict__ first_cp,
    float* attr_b, float* ranksum_b, float* nuniq_b) {
    __shared__ float red[3][8];
    int b = blockIdx.x, k = threadIdx.x;
    int v = cnt_packed[b * K_INST + k];
    int ncp = v & 0xFFFFF, cpc = v >> 20;
    int counts = ncp + cpc;
    int fc = first_cp[b * K_INST + k];
    bool has_cp = fc < N_HITS, exists = counts > 0;
    float attr = (has_cp && exists) ? seg_d2[b * K_INST + k] / fmaxf((float)counts, 1.f) : 0.f;
    float rank = (cpc == 1 && ncp > 0) ? seg_r[b * K_INST + k] / fmaxf((float)ncp, 1.f) : 0.f;
    float uq = exists ? 1.f : 0.f;
    for (int o = 32; o > 0; o >>= 1) {
        attr += __shfl_down(attr, o);
        rank += __shfl_down(rank, o);
        uq   += __shfl_down(uq, o);
    }
    int wave = k >> 6;
    if ((k & 63) == 0) { red[0][wave] = attr; red[1][wave] = rank; red[2][wave] = uq; }
    __syncthreads();
    if (k == 0) {
        float a = 0.f, r = 0.f, u = 0.f;
        for (int w = 0; w < 8; ++w) { a += red[0][w]; r += red[1][w]; u += red[2][w]; }
        attr_b[b] = a; ranksum_b[b] = r; nuniq_b[b] = u;
    }
}

// ---------------------------------------------------------------------------
// Kernel 5: repulsion. 2 k1-rows in registers x 32-row k2 tile in LDS.
// Grid = B*16 blocks of 256 threads.
// ---------------------------------------------------------------------------
__global__ __launch_bounds__(256) void k_rep(const float4* __restrict__ cp_emb4, float* rep_b) {
    __shared__ float4 tile[32 * 8];    // 4 KB
    __shared__ float red[4];
    int b  = blockIdx.x >> 4;
    int t2 = blockIdx.x & 15;
    int tid = threadIdx.x;
    const float4* base = cp_emb4 + (size_t)b * K_INST * 8;

    float4 r0[8], r1[8];
#pragma unroll
    for (int c = 0; c < 8; ++c) {
        r0[c] = base[(size_t)(2 * tid) * 8 + c];
        r1[c] = base[(size_t)(2 * tid + 1) * 8 + c];
    }
    tile[tid] = base[(size_t)t2 * 256 + tid];   // rows t2*32 .. t2*32+31
    __syncthreads();

    float acc = 0.f;
    for (int j = 0; j < 32; ++j) {
        float d2a = 0.f, d2b = 0.f;
#pragma unroll
        for (int c = 0; c < 8; ++c) {
            float4 e = tile[j * 8 + c];
            float ax = r0[c].x - e.x, ay = r0[c].y - e.y, az = r0[c].z - e.z, aw = r0[c].w - e.w;
            d2a += ax * ax + ay * ay + az * az + aw * aw;
            float bx = r1[c].x - e.x, by = r1[c].y - e.y, bz = r1[c].z - e.z, bw = r1[c].w - e.w;
            d2b += bx * bx + by * by + bz * bz + bw * bw;
        }
        acc += __expf(-d2a) + __expf(-d2b);
    }
    for (int o = 32; o > 0; o >>= 1) acc += __shfl_down(acc, o);
    int wave = tid >> 6;
    if ((tid & 63) == 0) red[wave] = acc;
    __syncthreads();
    if (tid == 0) atomicAdd(&rep_b[b], red[0] + red[1] + red[2] + red[3]);
}

// ---------------------------------------------------------------------------
// Kernel 6: combine per-batch scalars, mean over B, write 4 outputs
// ---------------------------------------------------------------------------
__global__ void k_final(const int* __restrict__ pos_cnt,
                        const float* __restrict__ s_cp, const float* __restrict__ s_ncp,
                        const float* __restrict__ s_bg, const float* __restrict__ attr_b,
                        const float* __restrict__ ranksum_b, const float* __restrict__ nuniq_b,
                        const float* __restrict__ rep_b, float* out, int B) {
    int b = threadIdx.x;
    float loss = 0.f, bl = 0.f, at = 0.f, rp = 0.f;
    if (b < B) {
        float pos = (float)pos_cnt[b];
        float pw = ((float)N_HITS - pos) / (pos + 1e-6f);
        float bce = (pw * s_cp[b] + s_ncp[b] + 2.f * s_bg[b]) / (float)N_HITS;
        float rank = ranksum_b[b] / fmaxf(nuniq_b[b], 1.f);
        bl = bce + 2.f * rank;
        at = attr_b[b];
        rp = rep_b[b] / (float)(K_INST * K_INST);
        loss = bl + at + rp;
    }
    for (int o = 32; o > 0; o >>= 1) {
        loss += __shfl_down(loss, o);
        bl   += __shfl_down(bl, o);
        at   += __shfl_down(at, o);
        rp   += __shfl_down(rp, o);
    }
    if (b == 0) {
        float inv = 1.f / (float)B;
        out[0] = loss * inv;
        out[1] = bl * inv;
        out[2] = at * inv;
        out[3] = rp * inv;
    }
}

// ---------------------------------------------------------------------------
extern "C" void kernel_launch(void* const* d_in, const int* in_sizes, int n_in,
                              void* d_out, int out_size, void* d_ws, size_t ws_size,
                              hipStream_t stream) {
    const float*  beta   = (const float*)d_in[0];
    const float*  embed  = (const float*)d_in[1];
    const int*    sid    = (const int*)d_in[2];
    const int*    iscp   = (const int*)d_in[3];
    float* out = (float*)d_out;

    int BN = in_sizes[0];          // B*N
    int B  = BN / N_HITS;          // 16
    int BK = B * K_INST;           // 8192

    // workspace layout (bytes):
    //   [0,            4*BK)   cnt_packed  (zeroed)
    //   [4*BK,         8*BK)   seg_d2      (zeroed)
    //   [8*BK,        12*BK)   seg_r       (zeroed)
    //   [12*BK,  12*BK+32*B)   per-batch scalars: pos,scp,sncp,sbg,attr,rank,nuniq,rep (zeroed)
    //   [zb,        zb+4*BK)   first_cp    (memset 0x7F -> sentinel 2139062143 > N)
    //   [zb+4*BK,   zb+8*BK)   cp_beta     (fully written by k_gather)
    //   [zb+8*BK,  ... +1MB)   cp_emb      (fully written by k_gather)
    char* ws = (char*)d_ws;
    int*   cnt_packed = (int*)ws;
    float* seg_d2     = (float*)(ws + 4 * (size_t)BK);
    float* seg_r      = (float*)(ws + 8 * (size_t)BK);
    float* scal       = (float*)(ws + 12 * (size_t)BK);
    int*   pos_cnt  = (int*)scal;
    float* s_cp     = scal + 1 * B;
    float* s_ncp    = scal + 2 * B;
    float* s_bg     = scal + 3 * B;
    float* attr_b   = scal + 4 * B;
    float* rank_b   = scal + 5 * B;
    float* nuniq_b  = scal + 6 * B;
    float* rep_b    = scal + 7 * B;
    size_t zbytes = 12 * (size_t)BK + 32 * (size_t)B;   // 98816 for B=16
    int*    first_cp = (int*)(ws + zbytes);
    float*  cp_beta  = (float*)(ws + zbytes + 4 * (size_t)BK);
    float4* cp_emb4  = (float4*)(ws + zbytes + 8 * (size_t)BK);   // 16B aligned (164352 % 16 == 0)

    hipMemsetAsync(ws, 0, zbytes, stream);
    hipMemsetAsync(first_cp, 0x7F, 4 * (size_t)BK, stream);

    // 1: scan
    k_scan<<<dim3(16, B), 256, 0, stream>>>(sid, iscp, first_cp, pos_cnt);

    // 2: gather cp rows
    {
        int total = BK * 8;
        k_gather<<<(total + 255) / 256, 256, 0, stream>>>(beta, (const float4*)embed,
                                                          first_cp, cp_beta, cp_emb4, B);
    }

    // 3: main streaming pass
    k_main<<<dim3(BPB, B), 256, 0, stream>>>(beta, (const float4*)embed, sid, iscp,
                                             (const float4*)cp_emb4, cp_beta,
                                             cnt_packed, seg_d2, seg_r, s_cp, s_ncp, s_bg);

    // 4: per-segment finalize
    k_seg<<<B, 512, 0, stream>>>(cnt_packed, seg_d2, seg_r, first_cp,
                                 attr_b, rank_b, nuniq_b);

    // 5: repulsion
    k_rep<<<B * 16, 256, 0, stream>>>((const float4*)cp_emb4, rep_b);

    // 6: final combine
    k_final<<<1, 64, 0, stream>>>(pos_cnt, s_cp, s_ncp, s_bg, attr_b, rank_b,
                                  nuniq_b, rep_b, out, B);
}